// Round 1
// baseline (566.288 us; speedup 1.0000x reference)
//
#include <hip/hip_runtime.h>

#define N_NODES   100000
#define N_EDGES   1600000
#define F         128
#define N_CLASSES 47
#define SCAN_B    98   // ceil(N_NODES / 1024)

typedef unsigned int uint32;

typedef short  v8s __attribute__((ext_vector_type(8)));   // 8 x bf16 (MFMA A/B frag)
typedef float  v4f __attribute__((ext_vector_type(4)));   // MFMA C/D frag, also nt float4

// bf16 helpers (RNE)
__device__ __forceinline__ uint32 f2bf(float f) {
    uint32 u = __float_as_uint(f);
    return (u + 0x7FFFu + ((u >> 16) & 1u)) >> 16;
}
__device__ __forceinline__ float bfl(uint32 u) { return __uint_as_float(u << 16); }
__device__ __forceinline__ float bfh(uint32 u) { return __uint_as_float(u & 0xFFFF0000u); }

// ---------------- CSR build ----------------

__global__ void count_kernel(const int* __restrict__ dst, int* __restrict__ cnt) {
    int e = blockIdx.x * blockDim.x + threadIdx.x;
    if (e < N_EDGES) {
        int d = __builtin_nontemporal_load(&dst[e]);   // dead-after-read stream
        atomicAdd(&cnt[d], 1);
    }
}

__global__ void scan1_kernel(const int* __restrict__ cnt, int* __restrict__ blk_sums) {
    __shared__ int red[1024];
    int t = threadIdx.x;
    int i = blockIdx.x * 1024 + t;
    red[t] = (i < N_NODES) ? cnt[i] : 0;
    __syncthreads();
    #pragma unroll
    for (int off = 512; off > 0; off >>= 1) {
        if (t < off) red[t] += red[t + off];
        __syncthreads();
    }
    if (t == 0) blk_sums[blockIdx.x] = red[0];
}

__global__ void scan2_kernel(int* __restrict__ blk_sums, int* __restrict__ row_ptr) {
    __shared__ int s[128];
    int t = threadIdx.x;
    int v = (t < SCAN_B) ? blk_sums[t] : 0;
    s[t] = v;
    __syncthreads();
    #pragma unroll
    for (int off = 1; off < 128; off <<= 1) {
        int add = (t >= off) ? s[t - off] : 0;
        __syncthreads();
        s[t] += add;
        __syncthreads();
    }
    if (t < SCAN_B) blk_sums[t] = s[t] - v;     // exclusive offset
    if (t == SCAN_B - 1) row_ptr[N_NODES] = s[t];
}

__global__ void scan3_kernel(const int* __restrict__ cnt, const int* __restrict__ blk_offs,
                             int* __restrict__ row_ptr, float* __restrict__ rdeg) {
    __shared__ int s[1024];
    int t = threadIdx.x;
    int i = blockIdx.x * 1024 + t;
    int c = (i < N_NODES) ? cnt[i] : 0;
    s[t] = c;
    __syncthreads();
    #pragma unroll
    for (int off = 1; off < 1024; off <<= 1) {
        int add = (t >= off) ? s[t - off] : 0;
        __syncthreads();
        s[t] += add;
        __syncthreads();
    }
    if (i < N_NODES) {
        row_ptr[i] = s[t] - c + blk_offs[blockIdx.x];
        rdeg[i] = 1.0f / (float)max(c, 1);
    }
}

// XCD-grouped fill: group g = blockIdx&7 handles dst in [g*12500,(g+1)*12500).
// src/dst are dead-after-read streams -> nontemporal loads, so they don't evict
// the half-written dirty col lines (each group's col window ~800KB << 4MB L2).

__global__ void fill_kernel(const int* __restrict__ src, const int* __restrict__ dst,
                            const int* __restrict__ row_ptr, int* __restrict__ fillc,
                            int* __restrict__ col) {
    const int g  = blockIdx.x & 7;
    const int bi = blockIdx.x >> 3;
    const int nt = (gridDim.x >> 3) * 256;
    for (int e = bi * 256 + threadIdx.x; e < N_EDGES; e += nt) {
        int d = __builtin_nontemporal_load(&dst[e]);
        if (d / 12500 == g) {
            int s = __builtin_nontemporal_load(&src[e]);
            int p = row_ptr[d] + atomicAdd(&fillc[d], 1);
            col[p] = s;                      // normal store: wants L2 merging
        }
    }
}

// ---------------- weight pre-pack: fp32 Wn/Ws -> bf16 MFMA A-frags ----------------

__global__ void pack_w_kernel(const float* __restrict__ Wn, const float* __restrict__ Ws,
                              int nout, unsigned short* __restrict__ wfrag) {
    int tile = blockIdx.x;           // mt*8 + kt
    int kt   = tile & 7;
    int mt   = tile >> 3;
    int lane = threadIdx.x;          // 64
    int quad = lane >> 4;
    int m    = mt * 16 + (lane & 15);
    uint32 packed[4];
    #pragma unroll
    for (int jj = 0; jj < 4; ++jj) {
        uint32 lo = 0, hi = 0;
        #pragma unroll
        for (int b = 0; b < 2; ++b) {
            int j = jj * 2 + b;
            int k = kt * 32 + quad * 8 + j;
            float w = 0.f;
            if (m < nout) w = (k < F) ? Wn[(size_t)k * nout + m] : Ws[(size_t)(k - F) * nout + m];
            if (b == 0) lo = f2bf(w); else hi = f2bf(w);
        }
        packed[jj] = lo | (hi << 16);
    }
    uint4 o = make_uint4(packed[0], packed[1], packed[2], packed[3]);
    *(uint4*)(wfrag + ((size_t)tile * 64 + lane) * 8) = o;
}

// single-W pack (K=128, 4 k-tiles): tile = mt*4 + kt
__global__ void pack_w_single_kernel(const float* __restrict__ W, int nout,
                                     unsigned short* __restrict__ wfrag) {
    int tile = blockIdx.x;
    int kt   = tile & 3;
    int mt   = tile >> 2;
    int lane = threadIdx.x;
    int quad = lane >> 4;
    int m    = mt * 16 + (lane & 15);
    uint32 packed[4];
    #pragma unroll
    for (int jj = 0; jj < 4; ++jj) {
        uint32 lo = 0, hi = 0;
        #pragma unroll
        for (int b = 0; b < 2; ++b) {
            int k = kt * 32 + quad * 8 + jj * 2 + b;
            float w = (m < nout) ? W[(size_t)k * nout + m] : 0.f;
            if (b == 0) lo = f2bf(w); else hi = f2bf(w);
        }
        packed[jj] = lo | (hi << 16);
    }
    uint4 o = make_uint4(packed[0], packed[1], packed[2], packed[3]);
    *(uint4*)(wfrag + ((size_t)tile * 64 + lane) * 8) = o;
}

// ---------------- embedding gather: fp32 embed -> bf16 h ----------------

__global__ void gather_embed_kernel(const float* __restrict__ embed,
                                    const int* __restrict__ idx,
                                    unsigned short* __restrict__ h) {
    int i = blockIdx.x * blockDim.x + threadIdx.x;
    const int TOTAL = N_NODES * (F / 4);
    if (i < TOTAL) {
        int node = i >> 5;
        int c4 = i & 31;
        int nid = __builtin_nontemporal_load(&idx[node]);
        v4f v = __builtin_nontemporal_load((const v4f*)(embed + (size_t)nid * F) + c4);
        uint2 o;
        o.x = f2bf(v.x) | (f2bf(v.y) << 16);
        o.y = f2bf(v.z) | (f2bf(v.w) << 16);
        ((uint2*)(h + (size_t)node * F))[c4] = o;
    }
}

// ---------------- pull aggregation (bf16 h -> bf16 mean, fp32 accum) ----------------
// one wave per node; 4 sub-groups x 16 lanes; each sub-group loads a FULL
// 256B neighbor row as uint4 (16B/lane) -> 4 edges per iter. col is a
// dead-after-read stream -> nontemporal (protects hot h rows in L2).

__global__ void aggregate_kernel(const unsigned short* __restrict__ h,
                                 const int* __restrict__ row_ptr,
                                 const int* __restrict__ col,
                                 const float* __restrict__ rdeg,
                                 unsigned short* __restrict__ mean) {
    const int wave = threadIdx.x >> 6;
    const int lane = threadIdx.x & 63;
    const int sub  = lane >> 4;          // which of 4 edges per iter
    const int li   = lane & 15;          // 16B slot within the row
    const int v    = blockIdx.x * 4 + wave;
    if (v >= N_NODES) return;

    const uint4* hp4 = (const uint4*)h;  // 16 uint4 per 256B row
    const int beg = row_ptr[v], end = row_ptr[v + 1];

    float a0 = 0.f, a1 = 0.f, a2 = 0.f, a3 = 0.f;
    float a4 = 0.f, a5 = 0.f, a6 = 0.f, a7 = 0.f;

    int p = beg;
    int u = __builtin_nontemporal_load(&col[min(p + sub, N_EDGES - 1)]);
    #pragma unroll 2
    for (; p + 4 <= end; p += 4) {
        int un = __builtin_nontemporal_load(&col[min(p + 4 + sub, N_EDGES - 1)]);
        uint4 x = hp4[(size_t)u * 16 + li];
        a0 += bfl(x.x); a1 += bfh(x.x);
        a2 += bfl(x.y); a3 += bfh(x.y);
        a4 += bfl(x.z); a5 += bfh(x.z);
        a6 += bfl(x.w); a7 += bfh(x.w);
        u = un;
    }
    if (p + sub < end) {                      // tail (u already prefetched)
        uint4 x = hp4[(size_t)u * 16 + li];
        a0 += bfl(x.x); a1 += bfh(x.x);
        a2 += bfl(x.y); a3 += bfh(x.y);
        a4 += bfl(x.z); a5 += bfh(x.z);
        a6 += bfl(x.w); a7 += bfh(x.w);
    }

    #pragma unroll
    for (int m = 16; m <= 32; m <<= 1) {
        a0 += __shfl_xor(a0, m, 64);
        a1 += __shfl_xor(a1, m, 64);
        a2 += __shfl_xor(a2, m, 64);
        a3 += __shfl_xor(a3, m, 64);
        a4 += __shfl_xor(a4, m, 64);
        a5 += __shfl_xor(a5, m, 64);
        a6 += __shfl_xor(a6, m, 64);
        a7 += __shfl_xor(a7, m, 64);
    }

    if (sub == 0) {
        const float r = rdeg[v];
        uint4 o;
        o.x = f2bf(a0 * r) | (f2bf(a1 * r) << 16);
        o.y = f2bf(a2 * r) | (f2bf(a3 * r) << 16);
        o.z = f2bf(a4 * r) | (f2bf(a5 * r) << 16);
        o.w = f2bf(a6 * r) | (f2bf(a7 * r) << 16);
        ((uint4*)mean)[(size_t)v * 16 + li] = o;
    }
}

// 48-wide aggregation over 128B rows (layer 2, post-transform).
// 8 sub-groups x 8 lanes; each sub-group loads a full 128B row (uint4/lane).

__global__ void aggregate48_kernel(const unsigned short* __restrict__ hn,
                                   const int* __restrict__ row_ptr,
                                   const int* __restrict__ col,
                                   const float* __restrict__ rdeg,
                                   unsigned short* __restrict__ mean) {
    const int wave = threadIdx.x >> 6;
    const int lane = threadIdx.x & 63;
    const int sub  = lane >> 3;          // which of 8 edges per iter
    const int li   = lane & 7;           // 16B slot within the 128B row
    const int v    = blockIdx.x * 4 + wave;
    if (v >= N_NODES) return;

    const uint4* hp4 = (const uint4*)hn; // 8 uint4 per 128B row
    const int beg = row_ptr[v], end = row_ptr[v + 1];

    float a0 = 0.f, a1 = 0.f, a2 = 0.f, a3 = 0.f;
    float a4 = 0.f, a5 = 0.f, a6 = 0.f, a7 = 0.f;

    int p = beg;
    int u = __builtin_nontemporal_load(&col[min(p + sub, N_EDGES - 1)]);
    #pragma unroll 2
    for (; p + 8 <= end; p += 8) {
        int un = __builtin_nontemporal_load(&col[min(p + 8 + sub, N_EDGES - 1)]);
        uint4 x = hp4[(size_t)u * 8 + li];
        a0 += bfl(x.x); a1 += bfh(x.x);
        a2 += bfl(x.y); a3 += bfh(x.y);
        a4 += bfl(x.z); a5 += bfh(x.z);
        a6 += bfl(x.w); a7 += bfh(x.w);
        u = un;
    }
    if (p + sub < end) {
        uint4 x = hp4[(size_t)u * 8 + li];
        a0 += bfl(x.x); a1 += bfh(x.x);
        a2 += bfl(x.y); a3 += bfh(x.y);
        a4 += bfl(x.z); a5 += bfh(x.z);
        a6 += bfl(x.w); a7 += bfh(x.w);
    }

    #pragma unroll
    for (int m = 8; m <= 32; m <<= 1) {
        a0 += __shfl_xor(a0, m, 64);
        a1 += __shfl_xor(a1, m, 64);
        a2 += __shfl_xor(a2, m, 64);
        a3 += __shfl_xor(a3, m, 64);
        a4 += __shfl_xor(a4, m, 64);
        a5 += __shfl_xor(a5, m, 64);
        a6 += __shfl_xor(a6, m, 64);
        a7 += __shfl_xor(a7, m, 64);
    }

    if (sub == 0) {
        const float r = rdeg[v];
        uint4 o;
        o.x = f2bf(a0 * r) | (f2bf(a1 * r) << 16);
        o.y = f2bf(a2 * r) | (f2bf(a3 * r) << 16);
        o.z = f2bf(a4 * r) | (f2bf(a5 * r) << 16);
        o.w = f2bf(a6 * r) | (f2bf(a7 * r) << 16);
        ((uint4*)mean)[(size_t)v * 8 + li] = o;
    }
}

// ---------------- MFMA GEMM: out = [mean|h] @ Wcat + b (+relu), bf16 out ----------------

template<int MT, bool RELU>
__global__ __launch_bounds__(256)
void mfma_gemm_kernel(const unsigned short* __restrict__ meanb,
                      const unsigned short* __restrict__ h,
                      const unsigned short* __restrict__ wfrag,
                      const float* __restrict__ bias,
                      unsigned short* __restrict__ out) {
    const int lane = threadIdx.x & 63;
    const int wave = threadIdx.x >> 6;
    const int quad = lane >> 4;
    const int nn   = lane & 15;
    const int base = blockIdx.x * 128 + wave * 32;

    const int n0 = base + nn;
    const int n1 = base + 16 + nn;
    const size_t r0 = (size_t)min(n0, N_NODES - 1) * F;
    const size_t r1 = (size_t)min(n1, N_NODES - 1) * F;

    v4f acc[MT][2];
    #pragma unroll
    for (int mt = 0; mt < MT; ++mt) { acc[mt][0] = (v4f)0.f; acc[mt][1] = (v4f)0.f; }

    #pragma unroll
    for (int kt = 0; kt < 8; ++kt) {
        const unsigned short* B = (kt < 4) ? meanb : h;
        const int koff = (kt & 3) * 32 + quad * 8;
        // B rows are read exactly once (dead after this GEMM) -> nontemporal,
        // protects the freshly-written output h of this layer in L2.
        v8s b0 = __builtin_nontemporal_load((const v8s*)(B + r0 + koff));
        v8s b1 = __builtin_nontemporal_load((const v8s*)(B + r1 + koff));
        #pragma unroll
        for (int mt = 0; mt < MT; ++mt) {
            v8s a = *(const v8s*)(wfrag + ((size_t)(mt * 8 + kt) * 64 + lane) * 8);
            acc[mt][0] = __builtin_amdgcn_mfma_f32_16x16x32_bf16(a, b0, acc[mt][0], 0, 0, 0);
            acc[mt][1] = __builtin_amdgcn_mfma_f32_16x16x32_bf16(a, b1, acc[mt][1], 0, 0, 0);
        }
    }

    #pragma unroll
    for (int mt = 0; mt < MT; ++mt) {
        const int m0 = mt * 16 + quad * 4;
        #pragma unroll
        for (int nt = 0; nt < 2; ++nt) {
            const int node = base + nt * 16 + nn;
            if (node >= N_NODES) continue;
            v4f a = acc[mt][nt];
            const float4 bb = *(const float4*)(bias + m0);
            float x0 = a[0] + bb.x, x1 = a[1] + bb.y, x2 = a[2] + bb.z, x3 = a[3] + bb.w;
            if (RELU) {
                x0 = fmaxf(x0, 0.f); x1 = fmaxf(x1, 0.f);
                x2 = fmaxf(x2, 0.f); x3 = fmaxf(x3, 0.f);
            }
            uint2 o;
            o.x = f2bf(x0) | (f2bf(x1) << 16);
            o.y = f2bf(x2) | (f2bf(x3) << 16);
            *(uint2*)(out + (size_t)node * F + m0) = o;
        }
    }
}

// ---------------- layer-2: hn2 = h @ Wn2 (bf16 out, row stride 64) ----------------
// mean is linear: mean(h) @ Wn2 == mean(h @ Wn2). Transform first so the
// per-edge gather reads 128B rows instead of 256B.

__global__ __launch_bounds__(256)
void gemm_hn2_kernel(const unsigned short* __restrict__ h,
                     const unsigned short* __restrict__ wfrag,
                     unsigned short* __restrict__ hn2) {
    const int lane = threadIdx.x & 63;
    const int wave = threadIdx.x >> 6;
    const int quad = lane >> 4;
    const int nn   = lane & 15;
    const int base = blockIdx.x * 128 + wave * 32;

    const int n0 = base + nn;
    const int n1 = base + 16 + nn;
    const size_t r0 = (size_t)min(n0, N_NODES - 1) * F;
    const size_t r1 = (size_t)min(n1, N_NODES - 1) * F;

    v4f acc[3][2];
    #pragma unroll
    for (int mt = 0; mt < 3; ++mt) { acc[mt][0] = (v4f)0.f; acc[mt][1] = (v4f)0.f; }

    #pragma unroll
    for (int kt = 0; kt < 4; ++kt) {
        const int koff = kt * 32 + quad * 8;
        // h is re-read by final_kernel -> NO nontemporal here
        v8s b0 = *(const v8s*)(h + r0 + koff);
        v8s b1 = *(const v8s*)(h + r1 + koff);
        #pragma unroll
        for (int mt = 0; mt < 3; ++mt) {
            v8s a = *(const v8s*)(wfrag + ((size_t)(mt * 4 + kt) * 64 + lane) * 8);
            acc[mt][0] = __builtin_amdgcn_mfma_f32_16x16x32_bf16(a, b0, acc[mt][0], 0, 0, 0);
            acc[mt][1] = __builtin_amdgcn_mfma_f32_16x16x32_bf16(a, b1, acc[mt][1], 0, 0, 0);
        }
    }

    #pragma unroll
    for (int mt = 0; mt < 3; ++mt) {
        const int m0 = mt * 16 + quad * 4;   // 0..47
        #pragma unroll
        for (int nt = 0; nt < 2; ++nt) {
            const int node = base + nt * 16 + nn;
            if (node >= N_NODES) continue;
            v4f a = acc[mt][nt];
            uint2 o;
            o.x = f2bf(a[0]) | (f2bf(a[1]) << 16);
            o.y = f2bf(a[2]) | (f2bf(a[3]) << 16);
            *(uint2*)(hn2 + (size_t)node * 64 + m0) = o;
        }
    }
}

// ---------------- layer-2 final: out = mean2 + h @ Ws2 + b2 (fp32 out) ----------------

__global__ __launch_bounds__(256)
void final_kernel(const unsigned short* __restrict__ h,
                  const unsigned short* __restrict__ mean2,
                  const unsigned short* __restrict__ wfrag,
                  const float* __restrict__ bias,
                  float* __restrict__ out) {
    const int lane = threadIdx.x & 63;
    const int wave = threadIdx.x >> 6;
    const int quad = lane >> 4;
    const int nn   = lane & 15;
    const int base = blockIdx.x * 128 + wave * 32;

    const int n0 = base + nn;
    const int n1 = base + 16 + nn;
    const size_t r0 = (size_t)min(n0, N_NODES - 1) * F;
    const size_t r1 = (size_t)min(n1, N_NODES - 1) * F;

    v4f acc[3][2];
    #pragma unroll
    for (int mt = 0; mt < 3; ++mt) { acc[mt][0] = (v4f)0.f; acc[mt][1] = (v4f)0.f; }

    #pragma unroll
    for (int kt = 0; kt < 4; ++kt) {
        const int koff = kt * 32 + quad * 8;
        // last use of h -> nontemporal
        v8s b0 = __builtin_nontemporal_load((const v8s*)(h + r0 + koff));
        v8s b1 = __builtin_nontemporal_load((const v8s*)(h + r1 + koff));
        #pragma unroll
        for (int mt = 0; mt < 3; ++mt) {
            v8s a = *(const v8s*)(wfrag + ((size_t)(mt * 4 + kt) * 64 + lane) * 8);
            acc[mt][0] = __builtin_amdgcn_mfma_f32_16x16x32_bf16(a, b0, acc[mt][0], 0, 0, 0);
            acc[mt][1] = __builtin_amdgcn_mfma_f32_16x16x32_bf16(a, b1, acc[mt][1], 0, 0, 0);
        }
    }

    #pragma unroll
    for (int mt = 0; mt < 3; ++mt) {
        const int m0 = mt * 16 + quad * 4;   // 0..47, multiple of 4
        #pragma unroll
        for (int nt = 0; nt < 2; ++nt) {
            const int node = base + nt * 16 + nn;
            if (node >= N_NODES) continue;
            v4f a = acc[mt][nt];
            uint2 mv = *(const uint2*)(mean2 + (size_t)node * 64 + m0);
            float mf[4] = { bfl(mv.x), bfh(mv.x), bfl(mv.y), bfh(mv.y) };
            #pragma unroll
            for (int r = 0; r < 4; ++r) {
                int m = m0 + r;
                if (m < N_CLASSES)
                    out[(size_t)node * N_CLASSES + m] = a[r] + bias[m] + mf[r];
            }
        }
    }
}

// ---------------- launch ----------------

extern "C" void kernel_launch(void* const* d_in, const int* in_sizes, int n_in,
                              void* d_out, int out_size, void* d_ws, size_t ws_size,
                              hipStream_t stream) {
    const float* embed = (const float*)d_in[0];
    const float* Ws0   = (const float*)d_in[1];
    const float* Wn0   = (const float*)d_in[2];
    const float* b0    = (const float*)d_in[3];
    const float* Ws1   = (const float*)d_in[4];
    const float* Wn1   = (const float*)d_in[5];
    const float* b1    = (const float*)d_in[6];
    const float* Ws2   = (const float*)d_in[7];
    const float* Wn2   = (const float*)d_in[8];
    const float* b2    = (const float*)d_in[9];
    const int* input_nodes = (const int*)d_in[10];
    const int* src     = (const int*)d_in[11];
    const int* dst     = (const int*)d_in[12];
    float* out = (float*)d_out;

    char* ws = (char*)d_ws;
    size_t off = 0;
    auto alloc = [&](size_t bytes) -> void* {
        void* p = ws + off;
        off += (bytes + 255) & ~(size_t)255;
        return p;
    };
    int*            cnt      = (int*)           alloc(sizeof(int)   * N_NODES);
    int*            fillc    = (int*)           alloc(sizeof(int)   * N_NODES);
    int*            row_ptr  = (int*)           alloc(sizeof(int)   * (N_NODES + 1));
    float*          rdeg     = (float*)         alloc(sizeof(float) * N_NODES);
    int*            col      = (int*)           alloc(sizeof(int)   * N_EDGES);
    int*            blk_sums = (int*)           alloc(sizeof(int)   * 128);
    unsigned short* h_a      = (unsigned short*)alloc(2 * (size_t)N_NODES * F);
    unsigned short* h_b      = (unsigned short*)alloc(2 * (size_t)N_NODES * F);
    unsigned short* meanb    = (unsigned short*)alloc(2 * (size_t)N_NODES * F);
    unsigned short* wf0      = (unsigned short*)alloc(2 * 64 * 512);
    unsigned short* wf1      = (unsigned short*)alloc(2 * 64 * 512);
    unsigned short* wf2n     = (unsigned short*)alloc(2 * 12 * 512);
    unsigned short* wf2s     = (unsigned short*)alloc(2 * 12 * 512);
    (void)ws_size; (void)n_in; (void)in_sizes; (void)out_size;

    hipMemsetAsync(cnt,   0, sizeof(int) * N_NODES, stream);
    hipMemsetAsync(fillc, 0, sizeof(int) * N_NODES, stream);

    const int EB = (N_EDGES + 255) / 256;
    count_kernel<<<EB, 256, 0, stream>>>(dst, cnt);
    scan1_kernel<<<SCAN_B, 1024, 0, stream>>>(cnt, blk_sums);
    scan2_kernel<<<1, 128, 0, stream>>>(blk_sums, row_ptr);
    scan3_kernel<<<SCAN_B, 1024, 0, stream>>>(cnt, blk_sums, row_ptr, rdeg);
    fill_kernel<<<5000, 256, 0, stream>>>(src, dst, row_ptr, fillc, col);

    pack_w_kernel<<<64, 64, 0, stream>>>(Wn0, Ws0, F, wf0);
    pack_w_kernel<<<64, 64, 0, stream>>>(Wn1, Ws1, F, wf1);
    pack_w_single_kernel<<<12, 64, 0, stream>>>(Wn2, N_CLASSES, wf2n);
    pack_w_single_kernel<<<12, 64, 0, stream>>>(Ws2, N_CLASSES, wf2s);

    gather_embed_kernel<<<(N_NODES * (F / 4) + 255) / 256, 256, 0, stream>>>(embed, input_nodes, h_a);

    const int AGG_B  = (N_NODES + 3) / 4;
    const int GEMM_B = (N_NODES + 127) / 128;

    // layer 0: h_a -> h_b
    aggregate_kernel<<<AGG_B, 256, 0, stream>>>(h_a, row_ptr, col, rdeg, meanb);
    mfma_gemm_kernel<8, true><<<GEMM_B, 256, 0, stream>>>(meanb, h_a, wf0, b0, h_b);
    // layer 1: h_b -> h_a
    aggregate_kernel<<<AGG_B, 256, 0, stream>>>(h_b, row_ptr, col, rdeg, meanb);
    mfma_gemm_kernel<8, true><<<GEMM_B, 256, 0, stream>>>(meanb, h_b, wf1, b1, h_a);
    // layer 2 (transform-first): hn2 = h_a @ Wn2 (rows padded to 64, reuse h_b);
    // mean2 = mean-aggregate(hn2) (reuse meanb); out = mean2 + h_a @ Ws2 + b2
    gemm_hn2_kernel<<<GEMM_B, 256, 0, stream>>>(h_a, wf2n, h_b);
    aggregate48_kernel<<<AGG_B, 256, 0, stream>>>(h_b, row_ptr, col, rdeg, meanb);
    final_kernel<<<GEMM_B, 256, 0, stream>>>(h_a, meanb, wf2s, b2, out);
}